// Round 11
// baseline (193.827 us; speedup 1.0000x reference)
//
#include <hip/hip_runtime.h>
#include <hip/hip_bf16.h>
#include <cstdint>

// Problem constants: B=2, T=2048, D_IN=D_OUT=1024, H=16, DH=64
#define SEQ_T 2048
#define DMODEL 1024
#define NHEAD 16
#define DHEAD 64

typedef __attribute__((ext_vector_type(8))) __bf16 bf16x8;
typedef __attribute__((ext_vector_type(4))) float floatx4;

static __device__ __forceinline__ uint16_t f2bf(float f) {
    union { float f; uint32_t u; } v; v.f = f;
    uint32_t r = v.u + 0x7FFFu + ((v.u >> 16) & 1u);   // RNE
    return (uint16_t)(r >> 16);
}

// -------- merged fp32->bf16 converts: z<4 weight transpose, z==4 x --------
// W_q (z==0) is pre-scaled by 0.125*log2(e): QK^T then emits s*C directly,
// so attention softmax is a single v_exp_f32 (exp2) per score.
__global__ void mha_cvt(const float* __restrict__ x, uint16_t* __restrict__ xb,
                        const float* __restrict__ W0, const float* __restrict__ W1,
                        const float* __restrict__ W2, const float* __restrict__ W3,
                        uint16_t* __restrict__ T0, uint16_t* __restrict__ T1,
                        uint16_t* __restrict__ T2, uint16_t* __restrict__ T3) {
    if (blockIdx.z == 4) {
        int base = (blockIdx.y * 16 + blockIdx.x) * 256 + threadIdx.x;
#pragma unroll
        for (int i = 0; i < 16; ++i) {
            int idx = base + i * 65536;
            float4 f = ((const float4*)x)[idx];
            union { uint16_t u[4]; uint64_t v; } o;
            o.u[0] = f2bf(f.x); o.u[1] = f2bf(f.y); o.u[2] = f2bf(f.z); o.u[3] = f2bf(f.w);
            ((uint64_t*)xb)[idx] = o.v;
        }
        return;
    }
    const float* W; uint16_t* Tt; float sc;
    switch (blockIdx.z) {
        case 0: W = W0; Tt = T0; sc = 0.125f * 1.44269504089f; break;
        case 1: W = W1; Tt = T1; sc = 1.f; break;
        case 2: W = W2; Tt = T2; sc = 1.f; break;
        default: W = W3; Tt = T3; sc = 1.f; break;
    }
    __shared__ float tile[64][65];
    const int c  = threadIdx.x & 63;
    const int r0 = threadIdx.x >> 6;
    const int R0 = blockIdx.y * 64, C0 = blockIdx.x * 64;
#pragma unroll
    for (int rr = 0; rr < 16; ++rr) {
        int r = r0 + rr * 4;
        tile[r][c] = W[(size_t)(R0 + r) * DMODEL + C0 + c];
    }
    __syncthreads();
#pragma unroll
    for (int rr = 0; rr < 16; ++rr) {
        int r = r0 + rr * 4;
        Tt[(size_t)(C0 + r) * DMODEL + R0 + c] = f2bf(tile[c][r] * sc);
    }
}

// ------ bf16 MFMA GEMM, 128M x 128N tile, BK=64, B^T input, swizzled ------
// m97's proven 128-square tile + BK=64: 32 MFMA/wave per barrier-drain,
// 16 drains total. Dynamic shared mem so MODE instantiations share one
// buffer (static __shared__ in multiple template instantiations SUMS).
// Swizzle: row r slot q' holds source sub-chunk q'^(r&7) -> 2-way-only.
// MODE 0: bf16 row-major out. MODE 1: Vt[(b*1024+col)*2048+t] via LDS
// transpose reusing staging smem (Ct[128][136], 34.8 KB).
template<int MODE>
__device__ __forceinline__ void gemm128_bk64(
    const uint16_t* __restrict__ A, const uint16_t* __restrict__ Bt,
    uint16_t* __restrict__ outB) {
    const int K = DMODEL, N = DMODEL;
    extern __shared__ char smem[];
    uint16_t* As = (uint16_t*)smem;                 // [128][64] 16 KB
    uint16_t* Bs = (uint16_t*)(smem + 16384);       // [128][64] 16 KB
    const int tid  = threadIdx.x;
    const int wave = tid >> 6;
    const int lane = tid & 63;
    const int m0 = blockIdx.y * 128;
    const int n0 = blockIdx.x * 128;
    const int lr   = lane & 15;
    const int quad = lane >> 4;
    const int wm = wave >> 1, wn = wave & 1;

    floatx4 acc[4][4];
#pragma unroll
    for (int i = 0; i < 4; ++i)
#pragma unroll
        for (int j = 0; j < 4; ++j) acc[i][j] = (floatx4)0.0f;

    for (int k0 = 0; k0 < K; k0 += 64) {
#pragma unroll
        for (int i = 0; i < 4; ++i) {               // A: 1024 chunks
            int c = i * 256 + tid;
            int r = c >> 3, s = (c & 7) ^ (r & 7);
            const uint16_t* g = A + (size_t)(m0 + r) * K + k0 + s * 8;
            __builtin_amdgcn_global_load_lds((const __attribute__((address_space(1))) void*)g,
                                             (__attribute__((address_space(3))) void*)(As + (size_t)c * 8), 16, 0, 0);
        }
#pragma unroll
        for (int i = 0; i < 4; ++i) {               // B: 1024 chunks
            int c = i * 256 + tid;
            int r = c >> 3, s = (c & 7) ^ (r & 7);
            const uint16_t* g = Bt + (size_t)(n0 + r) * K + k0 + s * 8;
            __builtin_amdgcn_global_load_lds((const __attribute__((address_space(1))) void*)g,
                                             (__attribute__((address_space(3))) void*)(Bs + (size_t)c * 8), 16, 0, 0);
        }
        __syncthreads();
#pragma unroll
        for (int ks = 0; ks < 2; ++ks) {            // two 32-wide k-halves
            bf16x8 af[4], bfr[4];
#pragma unroll
            for (int mi = 0; mi < 4; ++mi) {
                int row = wm * 64 + mi * 16 + lr;
                af[mi] = *(const bf16x8*)&As[row * 64 + (((ks * 4 + quad) ^ (row & 7)) << 3)];
            }
#pragma unroll
            for (int ni = 0; ni < 4; ++ni) {
                int row = wn * 64 + ni * 16 + lr;
                bfr[ni] = *(const bf16x8*)&Bs[row * 64 + (((ks * 4 + quad) ^ (row & 7)) << 3)];
            }
#pragma unroll
            for (int mi = 0; mi < 4; ++mi)
#pragma unroll
                for (int ni = 0; ni < 4; ++ni)
                    acc[mi][ni] = __builtin_amdgcn_mfma_f32_16x16x32_bf16(af[mi], bfr[ni], acc[mi][ni], 0, 0, 0);
        }
        __syncthreads();
    }
    if constexpr (MODE == 1) {
        // per-head transpose through reused smem, coalesced 16B stores
        uint16_t* Ct = (uint16_t*)smem;             // [128][136], 34.8 KB
        const int bb = m0 >> 11, t0 = m0 & 2047;
#pragma unroll
        for (int mi = 0; mi < 4; ++mi)
#pragma unroll
            for (int ni = 0; ni < 4; ++ni) {
                int cl = wn * 64 + ni * 16 + lr;
                int tl = wm * 64 + mi * 16 + quad * 4;
                int tls = tl ^ ((cl & 3) << 4);     // 2-way-only bank pattern
                union { uint16_t u[4]; uint64_t v8; } pk;
#pragma unroll
                for (int r = 0; r < 4; ++r) pk.u[r] = f2bf(acc[mi][ni][r]);
                *(uint64_t*)&Ct[cl * 136 + tls] = pk.v8;
            }
        __syncthreads();
#pragma unroll
        for (int k = 0; k < 8; ++k) {
            int c = k * 256 + tid;                  // 2048 chunks of 16B
            int cl = c >> 4, off = (c & 15) * 8;
            int offs = off ^ ((cl & 3) << 4);
            uint4 v = *(const uint4*)&Ct[cl * 136 + offs];
            *(uint4*)&outB[((size_t)(bb * 1024 + n0 + cl)) * 2048 + t0 + off] = v;
        }
    } else {
#pragma unroll
        for (int mi = 0; mi < 4; ++mi)
#pragma unroll
            for (int ni = 0; ni < 4; ++ni) {
                int col = n0 + wn * 64 + ni * 16 + lr;
#pragma unroll
                for (int r = 0; r < 4; ++r) {
                    int row = m0 + wm * 64 + mi * 16 + quad * 4 + r;
                    outB[(size_t)row * N + col] = f2bf(acc[mi][ni][r]);
                }
            }
    }
}

__global__ __launch_bounds__(256) void mha_gemm_qkv(
    const uint16_t* __restrict__ A,
    const uint16_t* __restrict__ Wq, const uint16_t* __restrict__ Wk, const uint16_t* __restrict__ Wv,
    uint16_t* __restrict__ Q, uint16_t* __restrict__ K, uint16_t* __restrict__ Vt) {
    switch (blockIdx.z) {
        case 0:  gemm128_bk64<0>(A, Wq, Q);  break;
        case 1:  gemm128_bk64<0>(A, Wk, K);  break;
        default: gemm128_bk64<1>(A, Wv, Vt); break;
    }
}

// ---- out-projection GEMM: 64M x 64N, BK=64, grid (16,64)=1024 = 4/CU ----
// Light tile (acc 16 VGPR) -> 16 waves/CU of TLP; R9 lesson: occupancy
// beats per-drain MFMA count when registers are the cost.
__global__ __launch_bounds__(256) void mha_gemm_out(
    const uint16_t* __restrict__ A, const uint16_t* __restrict__ Wot,
    float* __restrict__ out, const float* __restrict__ bias) {
    const int K = DMODEL, N = DMODEL;
    extern __shared__ char smem[];
    uint16_t* As = (uint16_t*)smem;                 // [64][64] 8 KB
    uint16_t* Bs = (uint16_t*)(smem + 8192);        // [64][64] 8 KB
    const int tid  = threadIdx.x;
    const int wave = tid >> 6;
    const int lane = tid & 63;
    const int m0 = blockIdx.y * 64;
    const int n0 = blockIdx.x * 64;
    const int lr   = lane & 15;
    const int quad = lane >> 4;

    floatx4 acc[4];
#pragma unroll
    for (int i = 0; i < 4; ++i) acc[i] = (floatx4)0.0f;

    for (int k0 = 0; k0 < K; k0 += 64) {
#pragma unroll
        for (int i = 0; i < 2; ++i) {               // A 512 chunks
            int c = i * 256 + tid;
            int r = c >> 3, s = (c & 7) ^ (r & 7);
            const uint16_t* g = A + (size_t)(m0 + r) * K + k0 + s * 8;
            __builtin_amdgcn_global_load_lds((const __attribute__((address_space(1))) void*)g,
                                             (__attribute__((address_space(3))) void*)(As + (size_t)c * 8), 16, 0, 0);
        }
#pragma unroll
        for (int i = 0; i < 2; ++i) {               // B 512 chunks
            int c = i * 256 + tid;
            int r = c >> 3, s = (c & 7) ^ (r & 7);
            const uint16_t* g = Wot + (size_t)(n0 + r) * K + k0 + s * 8;
            __builtin_amdgcn_global_load_lds((const __attribute__((address_space(1))) void*)g,
                                             (__attribute__((address_space(3))) void*)(Bs + (size_t)c * 8), 16, 0, 0);
        }
        __syncthreads();
#pragma unroll
        for (int ks = 0; ks < 2; ++ks) {
            bf16x8 af[4], bfr;
#pragma unroll
            for (int mi = 0; mi < 4; ++mi) {
                int row = mi * 16 + lr;
                af[mi] = *(const bf16x8*)&As[row * 64 + (((ks * 4 + quad) ^ (row & 7)) << 3)];
            }
            {
                int row = wave * 16 + lr;
                bfr = *(const bf16x8*)&Bs[row * 64 + (((ks * 4 + quad) ^ (row & 7)) << 3)];
            }
#pragma unroll
            for (int mi = 0; mi < 4; ++mi)
                acc[mi] = __builtin_amdgcn_mfma_f32_16x16x32_bf16(af[mi], bfr, acc[mi], 0, 0, 0);
        }
        __syncthreads();
    }
    int col = n0 + wave * 16 + lr;
    float bv = bias[col];
#pragma unroll
    for (int mi = 0; mi < 4; ++mi)
#pragma unroll
        for (int r = 0; r < 4; ++r) {
            int row = m0 + mi * 16 + quad * 4 + r;
            out[(size_t)row * N + col] = acc[mi][r] + bv;
        }
}

// ---------------- MFMA flash attention (causal, fixed-base softmax) -------
// Grid (h, p, b): XCD = linear%8 = h%8 -> one head's K/V stays in one XCD L2
// (R10-verified: FETCH 97 -> 12 MB). 4 waves / 256 thr; balanced pairing
// jH=31-p then jL=p (33 iters always). Async single-barrier dbuf staging.
// W_q pre-scaled by 0.125*log2e -> softmax p = exp2(s), one v_exp_f32.
__global__ __launch_bounds__(256) void mha_attn_mfma(
    const uint16_t* __restrict__ Q, const uint16_t* __restrict__ K,
    const uint16_t* __restrict__ Vt, uint16_t* __restrict__ ctx) {
    __shared__ alignas(16) uint16_t Ks[2][64 * 64];   // 16 KB
    __shared__ alignas(16) uint16_t Vs[2][64 * 64];   // 16 KB
    __shared__ alignas(16) uint16_t Pb[64 * 72];      // 9 KB

    const int tid  = threadIdx.x;
    const int wave = tid >> 6;
    const int lane = tid & 63;
    const int lr   = lane & 15;
    const int quad = lane >> 4;
    const int h  = blockIdx.x;             // head fastest -> XCD locality
    const int p  = blockIdx.y;             // 0..15
    const int b  = blockIdx.z;
    const int jH = 31 - p, jL = p;         // 64-row q-tiles
    const int TH = jH + 1;
    const int TL = jL + 1;
    const int Ttot = TH + TL;              // 33 for every block

    const uint16_t* kbase[2];
    const uint16_t* vbase[2];
#pragma unroll
    for (int i = 0; i < 2; ++i) {
        int c = i * 256 + tid;             // chunk 0..511 (16B each)
        int row = c >> 3, cs = c & 7;
        int csk = cs ^ (row & 7);          // XOR source swizzle; dest linear
        kbase[i] = K  + ((size_t)(b * SEQ_T) + row) * DMODEL + h * DHEAD + csk * 8;
        vbase[i] = Vt + ((size_t)(b * 1024 + h * DHEAD + row)) * 2048 + csk * 8;
    }

    int wrow = jH * 64 + wave * 16;        // this wave's q-row base
    bf16x8 qf0, qf1;
    {
        const size_t qb = ((size_t)(b * SEQ_T) + wrow + lr) * DMODEL + h * DHEAD;
        qf0 = *(const bf16x8*)(Q + qb + quad * 8);
        qf1 = *(const bf16x8*)(Q + qb + 32 + quad * 8);
    }
    floatx4 o[4];
#pragma unroll
    for (int nt = 0; nt < 4; ++nt) o[nt] = (floatx4)0.0f;
    float l[4] = {0.f, 0.f, 0.f, 0.f};

    auto stage = [&](int kv0, int buf) {
#pragma unroll
        for (int i = 0; i < 2; ++i) {
            const uint16_t* gk = kbase[i] + (size_t)kv0 * DMODEL;
            const uint16_t* gv = vbase[i] + kv0;
            uint16_t* lk = &Ks[buf][(i * 256 + wave * 64) * 8];
            uint16_t* lv = &Vs[buf][(i * 256 + wave * 64) * 8];
            __builtin_amdgcn_global_load_lds((const __attribute__((address_space(1))) void*)gk,
                                             (__attribute__((address_space(3))) void*)lk, 16, 0, 0);
            __builtin_amdgcn_global_load_lds((const __attribute__((address_space(1))) void*)gv,
                                             (__attribute__((address_space(3))) void*)lv, 16, 0, 0);
        }
    };
    auto epilogue = [&]() {
#pragma unroll
        for (int r = 0; r < 4; ++r) {
            float v = l[r];
            v += __shfl_xor(v, 1, 64);
            v += __shfl_xor(v, 2, 64);
            v += __shfl_xor(v, 4, 64);
            v += __shfl_xor(v, 8, 64);
            l[r] = 1.f / v;
        }
#pragma unroll
        for (int nt = 0; nt < 4; ++nt)
#pragma unroll
            for (int r = 0; r < 4; ++r) {
                size_t addr = ((size_t)(b * SEQ_T) + wrow + quad * 4 + r) * DMODEL + h * DHEAD + nt * 16 + lr;
                ctx[addr] = f2bf(o[nt][r] * l[r]);
            }
    };

    stage(0, 0);
    __syncthreads();                       // tile 0 ready
    int cur = 0;

    for (int t = 0; t < Ttot; ++t) {
        if (t + 1 < Ttot) {
            int nkv0 = ((t + 1 < TH) ? (t + 1) : (t + 1 - TH)) * 64;
            stage(nkv0, cur ^ 1);          // in flight behind compute
        }
        const int kv0 = ((t < TH) ? t : (t - TH)) * 64;

        floatx4 s[4];
#pragma unroll
        for (int nt = 0; nt < 4; ++nt) {
            s[nt] = (floatx4)0.0f;
            int krow = nt * 16 + lr;
#pragma unroll
            for (int ks = 0; ks < 2; ++ks) {
                bf16x8 kf = *(const bf16x8*)&Ks[cur][krow * 64 + (((ks * 4 + quad) ^ (lr & 7)) * 8)];
                s[nt] = __builtin_amdgcn_mfma_f32_16x16x32_bf16(ks ? qf1 : qf0, kf, s[nt], 0, 0, 0);
            }
        }
        if (kv0 + 63 > wrow) {
#pragma unroll
            for (int nt = 0; nt < 4; ++nt) {
                int kcol = kv0 + nt * 16 + lr;
#pragma unroll
                for (int r = 0; r < 4; ++r) {
                    int qrow = wrow + quad * 4 + r;
                    if (kcol > qrow) s[nt][r] = -3e38f;
                }
            }
        }
        // p = exp2(s) (scale pre-folded into W_q); truncate to bf16, keep
        // l consistent with the truncated numerator values
#pragma unroll
        for (int nt = 0; nt < 4; ++nt)
#pragma unroll
            for (int r = 0; r < 4; ++r) {
                float pe = exp2f(s[nt][r]);
                uint32_t pu = __float_as_uint(pe);
                l[r] += __uint_as_float(pu & 0xffff0000u);
                Pb[(wave * 16 + quad * 4 + r) * 72 + nt * 16 + lr] = (uint16_t)(pu >> 16);
            }
#pragma unroll
        for (int ks = 0; ks < 2; ++ks) {
            bf16x8 pfr = *(const bf16x8*)&Pb[(wave * 16 + lr) * 72 + ks * 32 + quad * 8];
#pragma unroll
            for (int nt = 0; nt < 4; ++nt) {
                int vrow = nt * 16 + lr;
                bf16x8 vf = *(const bf16x8*)&Vs[cur][vrow * 64 + (((ks * 4 + quad) ^ (lr & 7)) * 8)];
                o[nt] = __builtin_amdgcn_mfma_f32_16x16x32_bf16(pfr, vf, o[nt], 0, 0, 0);
            }
        }
        if (t == TH - 1) {
            epilogue();
            wrow = jL * 64 + wave * 16;
            const size_t qb = ((size_t)(b * SEQ_T) + wrow + lr) * DMODEL + h * DHEAD;
            qf0 = *(const bf16x8*)(Q + qb + quad * 8);
            qf1 = *(const bf16x8*)(Q + qb + 32 + quad * 8);
#pragma unroll
            for (int nt = 0; nt < 4; ++nt) o[nt] = (floatx4)0.0f;
#pragma unroll
            for (int r = 0; r < 4; ++r) l[r] = 0.f;
        }
        __syncthreads();
        cur ^= 1;
    }
    epilogue();                            // light q-tile output
}

extern "C" void kernel_launch(void* const* d_in, const int* in_sizes, int n_in,
                              void* d_out, int out_size, void* d_ws, size_t ws_size,
                              hipStream_t stream) {
    const float* x  = (const float*)d_in[0];
    const float* Wq = (const float*)d_in[1];
    const float* Wk = (const float*)d_in[2];
    const float* Wv = (const float*)d_in[3];
    const float* Wo = (const float*)d_in[4];
    const float* bo = (const float*)d_in[5];
    float* out = (float*)d_out;

    char* ws = (char*)d_ws;
    const size_t SZ_X = (size_t)4096 * DMODEL * 2;   // 8 MB
    const size_t SZ_W = (size_t)DMODEL * DMODEL * 2; // 2 MB
    size_t off = 0;
    uint16_t* xb  = (uint16_t*)(ws + off); off += SZ_X;
    uint16_t* wqt = (uint16_t*)(ws + off); off += SZ_W;
    uint16_t* wkt = (uint16_t*)(ws + off); off += SZ_W;
    uint16_t* wvt = (uint16_t*)(ws + off); off += SZ_W;
    uint16_t* wot = (uint16_t*)(ws + off); off += SZ_W;
    uint16_t* Qb  = (uint16_t*)(ws + off); off += SZ_X;
    uint16_t* Kb  = (uint16_t*)(ws + off); off += SZ_X;
    uint16_t* Vtb = (uint16_t*)(ws + off); off += SZ_X;  // per-head transposed V
    uint16_t* Cb  = (uint16_t*)(ws + off); off += SZ_X;
    (void)ws_size; (void)in_sizes; (void)n_in; (void)out_size;

    mha_cvt<<<dim3(16, 16, 5), 256, 0, stream>>>(x, xb, Wq, Wk, Wv, Wo, wqt, wkt, wvt, wot);
    mha_gemm_qkv<<<dim3(8, 32, 3), 256, 34816, stream>>>(xb, wqt, wkt, wvt, Qb, Kb, Vtb);
    mha_attn_mfma<<<dim3(NHEAD, 16, 2), 256, 0, stream>>>(Qb, Kb, Vtb, Cb);
    mha_gemm_out<<<dim3(16, 64), 256, 16384, stream>>>(Cb, wot, out, bo);
}

// Round 12
// 178.967 us; speedup vs baseline: 1.0830x; 1.0830x over previous
//
#include <hip/hip_runtime.h>
#include <hip/hip_bf16.h>
#include <cstdint>

// Problem constants: B=2, T=2048, D_IN=D_OUT=1024, H=16, DH=64
#define SEQ_T 2048
#define DMODEL 1024
#define NHEAD 16
#define DHEAD 64

typedef __attribute__((ext_vector_type(8))) __bf16 bf16x8;
typedef __attribute__((ext_vector_type(4))) float floatx4;

static __device__ __forceinline__ uint16_t f2bf(float f) {
    union { float f; uint32_t u; } v; v.f = f;
    uint32_t r = v.u + 0x7FFFu + ((v.u >> 16) & 1u);   // RNE
    return (uint16_t)(r >> 16);
}

// -------- merged fp32->bf16 converts: z<4 weight transpose, z==4 x --------
// W_q (z==0) pre-scaled by 0.125*log2(e): QK^T emits s*C directly, so the
// attention softmax is a single raw v_exp_f32 (__builtin_amdgcn_exp2f).
__global__ void mha_cvt(const float* __restrict__ x, uint16_t* __restrict__ xb,
                        const float* __restrict__ W0, const float* __restrict__ W1,
                        const float* __restrict__ W2, const float* __restrict__ W3,
                        uint16_t* __restrict__ T0, uint16_t* __restrict__ T1,
                        uint16_t* __restrict__ T2, uint16_t* __restrict__ T3) {
    if (blockIdx.z == 4) {
        int base = (blockIdx.y * 16 + blockIdx.x) * 256 + threadIdx.x;
#pragma unroll
        for (int i = 0; i < 16; ++i) {
            int idx = base + i * 65536;
            float4 f = ((const float4*)x)[idx];
            union { uint16_t u[4]; uint64_t v; } o;
            o.u[0] = f2bf(f.x); o.u[1] = f2bf(f.y); o.u[2] = f2bf(f.z); o.u[3] = f2bf(f.w);
            ((uint64_t*)xb)[idx] = o.v;
        }
        return;
    }
    const float* W; uint16_t* Tt; float sc;
    switch (blockIdx.z) {
        case 0: W = W0; Tt = T0; sc = 0.125f * 1.44269504089f; break;
        case 1: W = W1; Tt = T1; sc = 1.f; break;
        case 2: W = W2; Tt = T2; sc = 1.f; break;
        default: W = W3; Tt = T3; sc = 1.f; break;
    }
    __shared__ float tile[64][65];
    const int c  = threadIdx.x & 63;
    const int r0 = threadIdx.x >> 6;
    const int R0 = blockIdx.y * 64, C0 = blockIdx.x * 64;
#pragma unroll
    for (int rr = 0; rr < 16; ++rr) {
        int r = r0 + rr * 4;
        tile[r][c] = W[(size_t)(R0 + r) * DMODEL + C0 + c];
    }
    __syncthreads();
#pragma unroll
    for (int rr = 0; rr < 16; ++rr) {
        int r = r0 + rr * 4;
        Tt[(size_t)(C0 + r) * DMODEL + R0 + c] = f2bf(tile[c][r] * sc);
    }
}

// ------ bf16 MFMA GEMM, 64M x 128N tile, BK=64, B^T input, swizzled ------
// (R10-proven shape.) BK=64: 16 MFMA/wave per barrier-drain, 16 drains.
// extern __shared__ so MODE instantiations SHARE one 24 KB buffer instead
// of summing to 49 KB (R8 evidence) -> 6 blocks/CU instead of 3.
// Swizzle: row r slot q' holds source sub-chunk q'^(r&7) -> 2-way-only.
// MODE 0: bf16 row-major out. MODE 1: Vt[(b*1024+col)*2048+t] via LDS
// transpose reusing staging smem. MODE 2: fp32 out + bias.
template<int MODE>
__device__ __forceinline__ void gemm_bk64_body(
    const uint16_t* __restrict__ A, const uint16_t* __restrict__ Bt,
    uint16_t* __restrict__ outB, float* __restrict__ outF,
    const float* __restrict__ bias) {
    const int K = DMODEL, N = DMODEL;
    extern __shared__ char smem[];                  // 24576 B dynamic
    uint16_t* As = (uint16_t*)smem;                 // [64][64]  8 KB
    uint16_t* Bs = (uint16_t*)(smem + 8192);        // [128][64] 16 KB
    const int tid  = threadIdx.x;
    const int wave = tid >> 6;
    const int lane = tid & 63;
    const int m0 = blockIdx.y * 64;
    const int n0 = blockIdx.x * 128;
    const int lr   = lane & 15;
    const int quad = lane >> 4;

    floatx4 acc[4][2];
#pragma unroll
    for (int i = 0; i < 4; ++i)
#pragma unroll
        for (int j = 0; j < 2; ++j) acc[i][j] = (floatx4)0.0f;

    for (int k0 = 0; k0 < K; k0 += 64) {
#pragma unroll
        for (int i = 0; i < 2; ++i) {               // A: 512 chunks (16B)
            int c = i * 256 + tid;
            int r = c >> 3, s = (c & 7) ^ (r & 7);
            const uint16_t* g = A + (size_t)(m0 + r) * K + k0 + s * 8;
            __builtin_amdgcn_global_load_lds((const __attribute__((address_space(1))) void*)g,
                                             (__attribute__((address_space(3))) void*)(As + (size_t)c * 8), 16, 0, 0);
        }
#pragma unroll
        for (int i = 0; i < 4; ++i) {               // B: 1024 chunks
            int c = i * 256 + tid;
            int r = c >> 3, s = (c & 7) ^ (r & 7);
            const uint16_t* g = Bt + (size_t)(n0 + r) * K + k0 + s * 8;
            __builtin_amdgcn_global_load_lds((const __attribute__((address_space(1))) void*)g,
                                             (__attribute__((address_space(3))) void*)(Bs + (size_t)c * 8), 16, 0, 0);
        }
        __syncthreads();
#pragma unroll
        for (int ks = 0; ks < 2; ++ks) {            // two 32-wide k-halves
            bf16x8 af[4], bfr[2];
#pragma unroll
            for (int mi = 0; mi < 4; ++mi) {
                int row = mi * 16 + lr;
                af[mi] = *(const bf16x8*)&As[row * 64 + (((ks * 4 + quad) ^ (row & 7)) << 3)];
            }
#pragma unroll
            for (int ni = 0; ni < 2; ++ni) {
                int row = wave * 32 + ni * 16 + lr;
                bfr[ni] = *(const bf16x8*)&Bs[row * 64 + (((ks * 4 + quad) ^ (row & 7)) << 3)];
            }
#pragma unroll
            for (int mi = 0; mi < 4; ++mi)
#pragma unroll
                for (int ni = 0; ni < 2; ++ni)
                    acc[mi][ni] = __builtin_amdgcn_mfma_f32_16x16x32_bf16(af[mi], bfr[ni], acc[mi][ni], 0, 0, 0);
        }
        __syncthreads();
    }
    if constexpr (MODE == 1) {
        // per-head transpose through reused smem, coalesced 16B stores
        uint16_t* Ct = (uint16_t*)smem;             // [128][72], 18.4 KB
        const int bb = m0 >> 11, t0 = m0 & 2047;
#pragma unroll
        for (int mi = 0; mi < 4; ++mi)
#pragma unroll
            for (int ni = 0; ni < 2; ++ni) {
                int cl = wave * 32 + ni * 16 + lr;
                int tl = mi * 16 + quad * 4;
                int tls = tl ^ ((cl & 3) << 4);     // 2-way-only bank pattern
                union { uint16_t u[4]; uint64_t v8; } pk;
#pragma unroll
                for (int r = 0; r < 4; ++r) pk.u[r] = f2bf(acc[mi][ni][r]);
                *(uint64_t*)&Ct[cl * 72 + tls] = pk.v8;
            }
        __syncthreads();
#pragma unroll
        for (int k = 0; k < 4; ++k) {
            int c = k * 256 + tid;                  // 1024 chunks of 16B
            int cl = c >> 3, off = (c & 7) * 8;
            int offs = off ^ ((cl & 3) << 4);
            uint4 v = *(const uint4*)&Ct[cl * 72 + offs];
            *(uint4*)&outB[((size_t)(bb * 1024 + n0 + cl)) * 2048 + t0 + off] = v;
        }
    } else if constexpr (MODE == 2) {
#pragma unroll
        for (int mi = 0; mi < 4; ++mi)
#pragma unroll
            for (int ni = 0; ni < 2; ++ni) {
                int col = n0 + wave * 32 + ni * 16 + lr;
                float bv = bias[col];
#pragma unroll
                for (int r = 0; r < 4; ++r) {
                    int row = m0 + mi * 16 + quad * 4 + r;
                    outF[(size_t)row * N + col] = acc[mi][ni][r] + bv;
                }
            }
    } else {
#pragma unroll
        for (int mi = 0; mi < 4; ++mi)
#pragma unroll
            for (int ni = 0; ni < 2; ++ni) {
                int col = n0 + wave * 32 + ni * 16 + lr;
#pragma unroll
                for (int r = 0; r < 4; ++r) {
                    int row = m0 + mi * 16 + quad * 4 + r;
                    outB[(size_t)row * N + col] = f2bf(acc[mi][ni][r]);
                }
            }
    }
}

__global__ __launch_bounds__(256) void mha_gemm_qkv(
    const uint16_t* __restrict__ A,
    const uint16_t* __restrict__ Wq, const uint16_t* __restrict__ Wk, const uint16_t* __restrict__ Wv,
    uint16_t* __restrict__ Q, uint16_t* __restrict__ K, uint16_t* __restrict__ Vt) {
    switch (blockIdx.z) {
        case 0:  gemm_bk64_body<0>(A, Wq, Q,  nullptr, nullptr); break;
        case 1:  gemm_bk64_body<0>(A, Wk, K,  nullptr, nullptr); break;
        default: gemm_bk64_body<1>(A, Wv, Vt, nullptr, nullptr); break;
    }
}

__global__ __launch_bounds__(256) void mha_gemm_out(
    const uint16_t* __restrict__ A, const uint16_t* __restrict__ Wot,
    float* __restrict__ out, const float* __restrict__ bias) {
    gemm_bk64_body<2>(A, Wot, nullptr, out, bias);
}

// ---------------- MFMA flash attention (causal, fixed-base softmax) -------
// Grid (h, p, b): XCD = linear%8 = h%8 -> one head's K/V stays in one XCD L2
// (R10-verified: FETCH 97 -> 12 MB). 4 waves / 256 thr; balanced pairing
// jH=31-p then jL=p (33 iters always). Async single-barrier dbuf staging.
// Softmax: W_q pre-scaled -> p = raw v_exp_f32 (amdgcn_exp2), no OCML.
// Pb: stride 64 with chunk-XOR swizzle -> total LDS 40 KB = 4 blocks/CU.
__global__ __launch_bounds__(256) void mha_attn_mfma(
    const uint16_t* __restrict__ Q, const uint16_t* __restrict__ K,
    const uint16_t* __restrict__ Vt, uint16_t* __restrict__ ctx) {
    __shared__ alignas(16) uint16_t Ks[2][64 * 64];   // 16 KB
    __shared__ alignas(16) uint16_t Vs[2][64 * 64];   // 16 KB
    __shared__ alignas(16) uint16_t Pb[64 * 64];      // 8 KB (swizzled)

    const int tid  = threadIdx.x;
    const int wave = tid >> 6;
    const int lane = tid & 63;
    const int lr   = lane & 15;
    const int quad = lane >> 4;
    const int h  = blockIdx.x;             // head fastest -> XCD locality
    const int p  = blockIdx.y;             // 0..15
    const int b  = blockIdx.z;
    const int jH = 31 - p, jL = p;         // 64-row q-tiles
    const int TH = jH + 1;
    const int TL = jL + 1;
    const int Ttot = TH + TL;              // 33 for every block

    const uint16_t* kbase[2];
    const uint16_t* vbase[2];
#pragma unroll
    for (int i = 0; i < 2; ++i) {
        int c = i * 256 + tid;             // chunk 0..511 (16B each)
        int row = c >> 3, cs = c & 7;
        int csk = cs ^ (row & 7);          // XOR source swizzle; dest linear
        kbase[i] = K  + ((size_t)(b * SEQ_T) + row) * DMODEL + h * DHEAD + csk * 8;
        vbase[i] = Vt + ((size_t)(b * 1024 + h * DHEAD + row)) * 2048 + csk * 8;
    }

    int wrow = jH * 64 + wave * 16;        // this wave's q-row base
    bf16x8 qf0, qf1;
    {
        const size_t qb = ((size_t)(b * SEQ_T) + wrow + lr) * DMODEL + h * DHEAD;
        qf0 = *(const bf16x8*)(Q + qb + quad * 8);
        qf1 = *(const bf16x8*)(Q + qb + 32 + quad * 8);
    }
    floatx4 o[4];
#pragma unroll
    for (int nt = 0; nt < 4; ++nt) o[nt] = (floatx4)0.0f;
    float l[4] = {0.f, 0.f, 0.f, 0.f};

    auto stage = [&](int kv0, int buf) {
#pragma unroll
        for (int i = 0; i < 2; ++i) {
            const uint16_t* gk = kbase[i] + (size_t)kv0 * DMODEL;
            const uint16_t* gv = vbase[i] + kv0;
            uint16_t* lk = &Ks[buf][(i * 256 + wave * 64) * 8];
            uint16_t* lv = &Vs[buf][(i * 256 + wave * 64) * 8];
            __builtin_amdgcn_global_load_lds((const __attribute__((address_space(1))) void*)gk,
                                             (__attribute__((address_space(3))) void*)lk, 16, 0, 0);
            __builtin_amdgcn_global_load_lds((const __attribute__((address_space(1))) void*)gv,
                                             (__attribute__((address_space(3))) void*)lv, 16, 0, 0);
        }
    };
    auto epilogue = [&]() {
#pragma unroll
        for (int r = 0; r < 4; ++r) {
            float v = l[r];
            v += __shfl_xor(v, 1, 64);
            v += __shfl_xor(v, 2, 64);
            v += __shfl_xor(v, 4, 64);
            v += __shfl_xor(v, 8, 64);
            l[r] = 1.f / v;
        }
#pragma unroll
        for (int nt = 0; nt < 4; ++nt)
#pragma unroll
            for (int r = 0; r < 4; ++r) {
                size_t addr = ((size_t)(b * SEQ_T) + wrow + quad * 4 + r) * DMODEL + h * DHEAD + nt * 16 + lr;
                ctx[addr] = f2bf(o[nt][r] * l[r]);
            }
    };

    stage(0, 0);
    __syncthreads();                       // tile 0 ready
    int cur = 0;

    for (int t = 0; t < Ttot; ++t) {
        if (t + 1 < Ttot) {
            int nkv0 = ((t + 1 < TH) ? (t + 1) : (t + 1 - TH)) * 64;
            stage(nkv0, cur ^ 1);          // in flight behind compute
        }
        const int kv0 = ((t < TH) ? t : (t - TH)) * 64;

        floatx4 s[4];
#pragma unroll
        for (int nt = 0; nt < 4; ++nt) {
            s[nt] = (floatx4)0.0f;
            int krow = nt * 16 + lr;
#pragma unroll
            for (int ks = 0; ks < 2; ++ks) {
                bf16x8 kf = *(const bf16x8*)&Ks[cur][krow * 64 + (((ks * 4 + quad) ^ (lr & 7)) * 8)];
                s[nt] = __builtin_amdgcn_mfma_f32_16x16x32_bf16(ks ? qf1 : qf0, kf, s[nt], 0, 0, 0);
            }
        }
        if (kv0 + 63 > wrow) {
#pragma unroll
            for (int nt = 0; nt < 4; ++nt) {
                int kcol = kv0 + nt * 16 + lr;
#pragma unroll
                for (int r = 0; r < 4; ++r) {
                    int qrow = wrow + quad * 4 + r;
                    if (kcol > qrow) s[nt][r] = -3e38f;
                }
            }
        }
        // p = exp2(s) via raw v_exp_f32 (scale folded into W_q); truncate
        // to bf16 and keep l consistent with the truncated numerator.
        // Pb write: row = wave*16+quad*4+r, key chunk (nt*2 + lr/8)
        // swizzled by row&7 -> b128 reads below are conflict-free.
#pragma unroll
        for (int nt = 0; nt < 4; ++nt)
#pragma unroll
            for (int r = 0; r < 4; ++r) {
                float pe = __builtin_amdgcn_exp2f(s[nt][r]);
                uint32_t pu = __float_as_uint(pe);
                l[r] += __uint_as_float(pu & 0xffff0000u);
                int row = wave * 16 + quad * 4 + r;
                int cc  = (nt * 2 + (lr >> 3)) ^ (row & 7);
                Pb[row * 64 + cc * 8 + (lr & 7)] = (uint16_t)(pu >> 16);
            }
#pragma unroll
        for (int ks = 0; ks < 2; ++ks) {
            int prow = wave * 16 + lr;
            bf16x8 pfr = *(const bf16x8*)&Pb[prow * 64 + (((ks * 4 + quad) ^ (prow & 7)) * 8)];
#pragma unroll
            for (int nt = 0; nt < 4; ++nt) {
                int vrow = nt * 16 + lr;
                bf16x8 vf = *(const bf16x8*)&Vs[cur][vrow * 64 + (((ks * 4 + quad) ^ (lr & 7)) * 8)];
                o[nt] = __builtin_amdgcn_mfma_f32_16x16x32_bf16(pfr, vf, o[nt], 0, 0, 0);
            }
        }
        if (t == TH - 1) {
            epilogue();
            wrow = jL * 64 + wave * 16;
            const size_t qb = ((size_t)(b * SEQ_T) + wrow + lr) * DMODEL + h * DHEAD;
            qf0 = *(const bf16x8*)(Q + qb + quad * 8);
            qf1 = *(const bf16x8*)(Q + qb + 32 + quad * 8);
#pragma unroll
            for (int nt = 0; nt < 4; ++nt) o[nt] = (floatx4)0.0f;
#pragma unroll
            for (int r = 0; r < 4; ++r) l[r] = 0.f;
        }
        __syncthreads();
        cur ^= 1;
    }
    epilogue();                            // light q-tile output
}

extern "C" void kernel_launch(void* const* d_in, const int* in_sizes, int n_in,
                              void* d_out, int out_size, void* d_ws, size_t ws_size,
                              hipStream_t stream) {
    const float* x  = (const float*)d_in[0];
    const float* Wq = (const float*)d_in[1];
    const float* Wk = (const float*)d_in[2];
    const float* Wv = (const float*)d_in[3];
    const float* Wo = (const float*)d_in[4];
    const float* bo = (const float*)d_in[5];
    float* out = (float*)d_out;

    char* ws = (char*)d_ws;
    const size_t SZ_X = (size_t)4096 * DMODEL * 2;   // 8 MB
    const size_t SZ_W = (size_t)DMODEL * DMODEL * 2; // 2 MB
    size_t off = 0;
    uint16_t* xb  = (uint16_t*)(ws + off); off += SZ_X;
    uint16_t* wqt = (uint16_t*)(ws + off); off += SZ_W;
    uint16_t* wkt = (uint16_t*)(ws + off); off += SZ_W;
    uint16_t* wvt = (uint16_t*)(ws + off); off += SZ_W;
    uint16_t* wot = (uint16_t*)(ws + off); off += SZ_W;
    uint16_t* Qb  = (uint16_t*)(ws + off); off += SZ_X;
    uint16_t* Kb  = (uint16_t*)(ws + off); off += SZ_X;
    uint16_t* Vtb = (uint16_t*)(ws + off); off += SZ_X;  // per-head transposed V
    uint16_t* Cb  = (uint16_t*)(ws + off); off += SZ_X;
    (void)ws_size; (void)in_sizes; (void)n_in; (void)out_size;

    mha_cvt<<<dim3(16, 16, 5), 256, 0, stream>>>(x, xb, Wq, Wk, Wv, Wo, wqt, wkt, wvt, wot);
    mha_gemm_qkv<<<dim3(8, 64, 3), 256, 24576, stream>>>(xb, wqt, wkt, wvt, Qb, Kb, Vtb);
    mha_attn_mfma<<<dim3(NHEAD, 16, 2), 256, 0, stream>>>(Qb, Kb, Vtb, Cb);
    mha_gemm_out<<<dim3(8, 64), 256, 24576, stream>>>(Cb, wot, out, bo);
}